// Round 6
// baseline (793.724 us; speedup 1.0000x reference)
//
#include <hip/hip_runtime.h>
#include <hip/hip_bf16.h>

#define V_ 32000
#define E_ 512
#define H_ 512
#define B_ 32
#define T_ 48
#define NWG 64          // recurrence workgroups (blocks 0..63)
#define NCON 250        // head-consumer workgroups
#define GRID (NWG + NCON)

typedef __attribute__((ext_vector_type(8))) short bf16x8;
typedef __attribute__((ext_vector_type(4))) float f32x4;
typedef __attribute__((ext_vector_type(4))) int   i32x4;
typedef __attribute__((ext_vector_type(2))) int   i32x2;

static __device__ __forceinline__ short f2bf(float f) {
  union { __hip_bfloat16 h; short s; } u;
  u.h = __float2bfloat16(f);
  return u.s;
}

static __device__ __forceinline__ bf16x8 load_cvt8(const float* p) {
  float4 a = *(const float4*)p;
  float4 b = *(const float4*)(p + 4);
  bf16x8 r;
  r[0] = f2bf(a.x); r[1] = f2bf(a.y); r[2] = f2bf(a.z); r[3] = f2bf(a.w);
  r[4] = f2bf(b.x); r[5] = f2bf(b.y); r[6] = f2bf(b.z); r[7] = f2bf(b.w);
  return r;
}

static __device__ __forceinline__ float sigf(float x) {
  return 1.0f / (1.0f + __expf(-x));
}
static __device__ __forceinline__ float tanh_fast(float x) {
  float e = __expf(2.0f * x);
  return (e - 1.0f) / (e + 1.0f);
}

// dependent-FMA burst: keeps the SIMD issuing real work between poll retries
// so DPM sees a busy chip (clock heater). ~256 cycles.
static __device__ __forceinline__ void heater() {
  float x = 1.000001f;
#pragma unroll
  for (int i = 0; i < 64; ++i) x = __builtin_fmaf(x, 1.000001f, 1e-8f);
  asm volatile("" :: "v"(x));
}

// 16 coherent dwordx4 loads, contiguous 256B, acked. "=&v": no alias w/ addr.
#define PLOADS16(T, ADDR)                                              \
  asm volatile(                                                        \
    "global_load_dwordx4 %0,  %16, off sc0 sc1\n\t"                    \
    "global_load_dwordx4 %1,  %16, off offset:16 sc0 sc1\n\t"          \
    "global_load_dwordx4 %2,  %16, off offset:32 sc0 sc1\n\t"          \
    "global_load_dwordx4 %3,  %16, off offset:48 sc0 sc1\n\t"          \
    "global_load_dwordx4 %4,  %16, off offset:64 sc0 sc1\n\t"          \
    "global_load_dwordx4 %5,  %16, off offset:80 sc0 sc1\n\t"          \
    "global_load_dwordx4 %6,  %16, off offset:96 sc0 sc1\n\t"          \
    "global_load_dwordx4 %7,  %16, off offset:112 sc0 sc1\n\t"         \
    "global_load_dwordx4 %8,  %16, off offset:128 sc0 sc1\n\t"         \
    "global_load_dwordx4 %9,  %16, off offset:144 sc0 sc1\n\t"         \
    "global_load_dwordx4 %10, %16, off offset:160 sc0 sc1\n\t"         \
    "global_load_dwordx4 %11, %16, off offset:176 sc0 sc1\n\t"         \
    "global_load_dwordx4 %12, %16, off offset:192 sc0 sc1\n\t"         \
    "global_load_dwordx4 %13, %16, off offset:208 sc0 sc1\n\t"         \
    "global_load_dwordx4 %14, %16, off offset:224 sc0 sc1\n\t"         \
    "global_load_dwordx4 %15, %16, off offset:240 sc0 sc1\n\t"         \
    "s_waitcnt vmcnt(0)"                                               \
    : "=&v"(T[0]),  "=&v"(T[1]),  "=&v"(T[2]),  "=&v"(T[3]),           \
      "=&v"(T[4]),  "=&v"(T[5]),  "=&v"(T[6]),  "=&v"(T[7]),           \
      "=&v"(T[8]),  "=&v"(T[9]),  "=&v"(T[10]), "=&v"(T[11]),          \
      "=&v"(T[12]), "=&v"(T[13]), "=&v"(T[14]), "=&v"(T[15])           \
    : "v"(ADDR) : "memory")

// 8 coherent dwordx4 loads, contiguous 128B, acked.
#define CLOADS8(T, ADDR)                                               \
  asm volatile(                                                        \
    "global_load_dwordx4 %0, %8, off sc0 sc1\n\t"                      \
    "global_load_dwordx4 %1, %8, off offset:16 sc0 sc1\n\t"            \
    "global_load_dwordx4 %2, %8, off offset:32 sc0 sc1\n\t"            \
    "global_load_dwordx4 %3, %8, off offset:48 sc0 sc1\n\t"            \
    "global_load_dwordx4 %4, %8, off offset:64 sc0 sc1\n\t"            \
    "global_load_dwordx4 %5, %8, off offset:80 sc0 sc1\n\t"            \
    "global_load_dwordx4 %6, %8, off offset:96 sc0 sc1\n\t"            \
    "global_load_dwordx4 %7, %8, off offset:112 sc0 sc1\n\t"           \
    "s_waitcnt vmcnt(0)"                                               \
    : "=&v"(T[0]), "=&v"(T[1]), "=&v"(T[2]), "=&v"(T[3]),              \
      "=&v"(T[4]), "=&v"(T[5]), "=&v"(T[6]), "=&v"(T[7])               \
    : "v"(ADDR) : "memory")

// tagged 8B store: {4B data, 4B tag} atomic as one instruction, no ack needed
#define TSTORE(ADDR, VAL)                                              \
  asm volatile("global_store_dwordx2 %0, %1, off sc0 sc1"              \
               :: "v"(ADDR), "v"(VAL) : "memory")

// ---------------------------------------------------------------------------
// Kernel 1: Xg[t][b][j] = x_t[b] @ W_ih^T [j] + b_ih[j] + b_hh[j]
// ---------------------------------------------------------------------------
__global__ __launch_bounds__(256) void k_xg(
    const float* __restrict__ img,   // [32][512]
    const int*   __restrict__ gt,    // [32][48]
    const float* __restrict__ emb,   // [32000][512]
    const float* __restrict__ W_ih,  // [2048][512]
    const float* __restrict__ b_ih,
    const float* __restrict__ b_hh,
    float* __restrict__ Xg)          // [48][32][2048]
{
  const int s    = blockIdx.x;
  const int lane = threadIdx.x & 63;
  const int wv   = threadIdx.x >> 6;
  const int nbase = blockIdx.y * 256 + wv * 64;
  const int lr  = lane & 15;
  const int lkb = lane >> 4;

  const float* arow[2];
#pragma unroll
  for (int m = 0; m < 2; ++m) {
    int b = m * 16 + lr;
    const float* src;
    if (s == 0) {
      src = img + b * E_;
    } else {
      int tok = (s == 1) ? 1 : gt[b * T_ + (s - 1)];
      src = emb + (long)tok * E_;
    }
    arow[m] = src;
  }

  f32x4 acc[2][4];
#pragma unroll
  for (int m = 0; m < 2; ++m)
#pragma unroll
    for (int n = 0; n < 4; ++n) acc[m][n] = (f32x4){0.f, 0.f, 0.f, 0.f};

  for (int kt = 0; kt < 16; ++kt) {
    int ko = kt * 32 + lkb * 8;
    bf16x8 a0 = load_cvt8(arow[0] + ko);
    bf16x8 a1 = load_cvt8(arow[1] + ko);
#pragma unroll
    for (int n = 0; n < 4; ++n) {
      const float* wp = W_ih + (long)(nbase + n * 16 + lr) * E_ + ko;
      bf16x8 bw = load_cvt8(wp);
      acc[0][n] = __builtin_amdgcn_mfma_f32_16x16x32_bf16(a0, bw, acc[0][n], 0, 0, 0);
      acc[1][n] = __builtin_amdgcn_mfma_f32_16x16x32_bf16(a1, bw, acc[1][n], 0, 0, 0);
    }
  }

#pragma unroll
  for (int n = 0; n < 4; ++n) {
    int j = nbase + n * 16 + lr;
    float bias = b_ih[j] + b_hh[j];
#pragma unroll
    for (int m = 0; m < 2; ++m) {
#pragma unroll
      for (int r = 0; r < 4; ++r) {
        int b = m * 16 + lkb * 4 + r;
        Xg[((long)(s * B_ + b) * 2048) + j] = acc[m][n][r] + bias;
      }
    }
  }
}

// ---------------------------------------------------------------------------
// Kernel 2 (fused): blocks 0..63 = LSTM recurrence (WG w owns 8 hidden dims,
// 32KB W_hh LDS); blocks 64..313 = head GEMM consumers.
// ALL cross-WG h traffic goes through tagged 8B units in hst:
//   unit(row, j) = { u32: 2 packed bf16 h[row][2j..2j+1], u32: tag }
//   rows 0..1503  = hs (step t>=1 stores row t-1, tag t+1)
//   rows 1504..1535 = h after the image step (t=0, tag 1)
// Producers poll the data units directly (tag==t) -> 2 round trips per step.
// Consumers poll their tile's units (tag == mt*16/32 + 2) with a heater burst
// between retries to keep SCLK up.
// ---------------------------------------------------------------------------
__global__ __launch_bounds__(256, 2) void k_fused(
    const float* __restrict__ W_hh,      // [2048][512]
    const float* __restrict__ Xg,        // [48][32][2048]
    const float* __restrict__ W_head,    // [32000][512]
    const float* __restrict__ b_head,    // [32000]
    char* __restrict__ hst,              // [1536][256] x 8B tagged units
    float* __restrict__ out)             // [48][32][32000]
{
  __shared__ __align__(16) char lds[69632];  // rec: 32K wlds + 32K stage + 4K gbuf
  const int tid  = threadIdx.x;
  const int lane = tid & 63;
  const int wv   = tid >> 6;
  const int lr   = lane & 15;
  const int lkb  = lane >> 4;

  if (blockIdx.x < NWG) {
    // ===================== recurrence role =====================
    char* wlds  = lds;            // [2 pair][16 kt][64 lane][16B] = 32KB
    char* stage = lds + 32768;    // pure h [32 b][512 dim] bf16, swizzled, 32KB
    char* gbufc = lds + 65536;    // [4 gate][32 b][8 dim] f32 = 4KB
    const int w = blockIdx.x;     // owns hidden dims [8w, 8w+8)
    const int p  = wv & 1;        // gate pair: gates 2p, 2p+1
    const int nt = wv >> 1;       // b-tile

    // preload W_hh fragments (waves 0,1 load pair wv)
    if (wv < 2) {
#pragma unroll
      for (int kt = 0; kt < 16; ++kt) {
        int g = 2 * wv + (lr >> 3);
        int row = g * 512 + w * 8 + (lr & 7);
        bf16x8 wf = load_cvt8(W_hh + (long)row * E_ + kt * 32 + lkb * 8);
        *(bf16x8*)(wlds + (((wv * 16 + kt) * 64) + lane) * 16) = wf;
      }
    }
    __syncthreads();

    // cell state: threads 0..127, b = tid>>2, local dims d0, d0+1
    const int cb_b  = tid >> 2;
    const int cb_d0 = (tid & 3) * 2;
    float c0 = 0.f, c1 = 0.f;

    for (int t = 0; t < T_; ++t) {
      const int bb = nt * 16 + lr;

      // Xg slice (cached loads; overlaps the poll)
      float4 xg = *(const float4*)(Xg + ((long)t * B_ + bb) * 2048 +
                                   (2 * p + (lkb >> 1)) * 512 + w * 8 + (lkb & 1) * 4);

      f32x4 acc = (f32x4){0.f, 0.f, 0.f, 0.f};

      if (t > 0) {
        // ---- poll tagged h units: thread owns b=tid>>3, units j0..j0+31 ----
        int rowbase = (t == 1) ? 1504 : (t - 2) * 32;
        int b_own = tid >> 3;
        const char* pb = hst + ((long)(rowbase + b_own) * 256 + (tid & 7) * 32) * 8;
        i32x4 u[16];
        while (true) {
          PLOADS16(u, pb);
          bool ok = true;
#pragma unroll
          for (int i = 0; i < 16; ++i)
            ok = ok && (u[i][1] == t) && (u[i][3] == t);
          if (ok) break;
          __builtin_amdgcn_s_sleep(1);
        }
        // ---- strip tags -> stage (pure bf16 [b][512], xor-swizzled) ----
        int j0b = (tid & 7) * 128;   // byte offset of this thread's data in row
#pragma unroll
        for (int c = 0; c < 8; ++c) {
          i32x4 pc = (i32x4){u[2 * c][0], u[2 * c][2], u[2 * c + 1][0], u[2 * c + 1][2]};
          *(i32x4*)(stage + b_own * 1024 + ((j0b + c * 16) ^ ((b_own & 7) << 4))) = pc;
        }
        __syncthreads();   // stage ready; also fences gbuf(t-1) cell reads

        // ---- MFMA: A = W rows (2 gates x 8 dims), B = h ----
#pragma unroll
        for (int kt = 0; kt < 16; ++kt) {
          bf16x8 a = *(const bf16x8*)(wlds + (((p * 16 + kt) * 64) + lane) * 16);
          i32x4 bv = *(const i32x4*)(stage + bb * 1024 +
                                     ((kt * 64 + lkb * 16) ^ ((bb & 7) << 4)));
          acc = __builtin_amdgcn_mfma_f32_16x16x32_bf16(a, *(bf16x8*)&bv, acc, 0, 0, 0);
        }
      }

      // add Xg, write gate exchange
      acc[0] += xg.x; acc[1] += xg.y; acc[2] += xg.z; acc[3] += xg.w;
      int gp = 2 * p + (lkb >> 1);
      *(f32x4*)(gbufc + (gp * 32 + bb) * 32 + (((lkb & 1) * 16) ^ ((bb & 1) << 4))) = acc;
      __syncthreads();

      // ---- cell update + tagged store (threads 0..127) ----
      if (tid < 128) {
        int b = cb_b, d0 = cb_d0;
        int blk = ((d0 >= 4) ? 16 : 0) ^ ((b & 1) << 4);
        int inn = (d0 & 3) * 4;
        float2 gi  = *(const float2*)(gbufc + (0 * 32 + b) * 32 + blk + inn);
        float2 gf  = *(const float2*)(gbufc + (1 * 32 + b) * 32 + blk + inn);
        float2 gg_ = *(const float2*)(gbufc + (2 * 32 + b) * 32 + blk + inn);
        float2 go  = *(const float2*)(gbufc + (3 * 32 + b) * 32 + blk + inn);

        float cn0 = sigf(gf.x) * c0 + sigf(gi.x) * tanh_fast(gg_.x);
        float cn1 = sigf(gf.y) * c1 + sigf(gi.y) * tanh_fast(gg_.y);
        c0 = cn0; c1 = cn1;
        unsigned short h0 = (unsigned short)f2bf(sigf(go.x) * tanh_fast(cn0));
        unsigned short h1 = (unsigned short)f2bf(sigf(go.y) * tanh_fast(cn1));
        i32x2 unit;
        unit[0] = (int)h0 | ((int)h1 << 16);
        unit[1] = t + 1;
        long row = (t == 0) ? (1504 + b) : ((long)(t - 1) * B_ + b);
        char* addr = hst + (row * 256 + w * 4 + (tid & 3)) * 8;
        TSTORE(addr, unit);
      }
      // no trailing sync: next step's poll/strip/sync provides ordering
    }
  } else {
    // ===================== head-consumer role =====================
    char* stage = lds;                        // 16KB hs m-tile, swizzled
    const int cid = blockIdx.x - NWG;         // 0..249, owns v [cid*128, +128)
    const int vA = cid * 128 + wv * 16 + lr;
    const int vB = vA + 64;

    bf16x8 bwA[16], bwB[16];
#pragma unroll
    for (int kt = 0; kt < 16; ++kt) {
      bwA[kt] = load_cvt8(W_head + (long)vA * E_ + kt * 32 + lkb * 8);
      bwB[kt] = load_cvt8(W_head + (long)vB * E_ + kt * 32 + lkb * 8);
    }
    float biasA = b_head[vA];
    float biasB = b_head[vB];

    for (int mt = 0; mt < 94; ++mt) {
      // poll this thread's 16 units of the tile (tag == mt*16/32 + 2)
      int row_l = tid >> 4;
      long rowg = (long)mt * 16 + row_l;
      const char* pb = hst + (rowg * 256 + (tid & 15) * 16) * 8;
      int tagneed = (mt * 16) / 32 + 2;
      i32x4 u[8];
      while (true) {
        CLOADS8(u, pb);
        bool ok = true;
#pragma unroll
        for (int i = 0; i < 8; ++i)
          ok = ok && (u[i][1] == tagneed) && (u[i][3] == tagneed);
        if (ok) break;
        heater();
      }
      __syncthreads();   // everyone done reading stage of previous tile

      // strip -> stage (pure bf16 [16 rows][1024B], swizzled)
      int j0b = (tid & 15) * 64;
#pragma unroll
      for (int c = 0; c < 4; ++c) {
        i32x4 pc = (i32x4){u[2 * c][0], u[2 * c][2], u[2 * c + 1][0], u[2 * c + 1][2]};
        *(i32x4*)(stage + row_l * 1024 + ((j0b + c * 16) ^ ((row_l & 7) << 4))) = pc;
      }
      __syncthreads();

      f32x4 accA = (f32x4){biasA, biasA, biasA, biasA};
      f32x4 accB = (f32x4){biasB, biasB, biasB, biasB};
#pragma unroll
      for (int kt = 0; kt < 16; ++kt) {
        int cb = kt * 64 + lkb * 16;
        i32x4 av = *(const i32x4*)(stage + lr * 1024 + (cb ^ ((lr & 7) << 4)));
        bf16x8 a = *(bf16x8*)&av;
        accA = __builtin_amdgcn_mfma_f32_16x16x32_bf16(a, bwA[kt], accA, 0, 0, 0);
        accB = __builtin_amdgcn_mfma_f32_16x16x32_bf16(a, bwB[kt], accB, 0, 0, 0);
      }

#pragma unroll
      for (int r = 0; r < 4; ++r) {
        int R = mt * 16 + lkb * 4 + r;          // hs row; out row = R + 32
        out[(long)(R + 32) * V_ + vA] = accA[r];
        out[(long)(R + 32) * V_ + vB] = accB[r];
      }
    }
  }
}

// ---------------------------------------------------------------------------
extern "C" void kernel_launch(void* const* d_in, const int* in_sizes, int n_in,
                              void* d_out, int out_size, void* d_ws, size_t ws_size,
                              hipStream_t stream) {
  const float* img  = (const float*)d_in[0];
  const int*   gt   = (const int*)d_in[1];
  const float* emb  = (const float*)d_in[2];
  const float* W_ih = (const float*)d_in[3];
  const float* W_hh = (const float*)d_in[4];
  const float* b_ih = (const float*)d_in[5];
  const float* b_hh = (const float*)d_in[6];
  const float* W_hd = (const float*)d_in[7];
  const float* b_hd = (const float*)d_in[8];
  float* out = (float*)d_out;

  char* ws = (char*)d_ws;
  char*  hst = ws;                                    // 1536*256*8 = 3145728 B
  float* Xg  = (float*)(ws + 3145728);                // 12582912 B

  hipMemsetAsync(hst, 0, 1536 * 256 * 8, stream);     // clear tags (replay safety)
  hipMemsetAsync(out, 0, (size_t)B_ * V_ * sizeof(float), stream);  // outputs[0]=0

  dim3 g1(48, 8);
  k_xg<<<g1, 256, 0, stream>>>(img, gt, emb, W_ih, b_ih, b_hh, Xg);
  k_fused<<<GRID, 256, 0, stream>>>(W_hh, Xg, W_hd, b_hd, hst, out);
}

// Round 7
// 354.518 us; speedup vs baseline: 2.2389x; 2.2389x over previous
//
#include <hip/hip_runtime.h>
#include <hip/hip_bf16.h>

#define V_ 32000
#define E_ 512
#define H_ 512
#define B_ 32
#define T_ 48
#define NWG 64          // recurrence workgroups (blocks 0..63)
#define NCON 250        // head-consumer workgroups (blocks 65..314)
#define GRID (NWG + 1 + NCON)
#define REP 8           // h-exchange replication factor

typedef __attribute__((ext_vector_type(8))) short bf16x8;
typedef __attribute__((ext_vector_type(4))) float f32x4;
typedef __attribute__((ext_vector_type(4))) int   i32x4;
typedef __attribute__((ext_vector_type(2))) int   i32x2;

static __device__ __forceinline__ short f2bf(float f) {
  union { __hip_bfloat16 h; short s; } u;
  u.h = __float2bfloat16(f);
  return u.s;
}

static __device__ __forceinline__ bf16x8 load_cvt8(const float* p) {
  float4 a = *(const float4*)p;
  float4 b = *(const float4*)(p + 4);
  bf16x8 r;
  r[0] = f2bf(a.x); r[1] = f2bf(a.y); r[2] = f2bf(a.z); r[3] = f2bf(a.w);
  r[4] = f2bf(b.x); r[5] = f2bf(b.y); r[6] = f2bf(b.z); r[7] = f2bf(b.w);
  return r;
}

static __device__ __forceinline__ float sigf(float x) {
  return 1.0f / (1.0f + __expf(-x));
}
static __device__ __forceinline__ float tanh_fast(float x) {
  float e = __expf(2.0f * x);
  return (e - 1.0f) / (e + 1.0f);
}

// coherent (sc0 sc1) 4B load, acked
static __device__ __forceinline__ unsigned prog_load(const unsigned* p) {
  unsigned v;
  asm volatile("global_load_dword %0, %1, off sc0 sc1\n\t"
               "s_waitcnt vmcnt(0)"
               : "=&v"(v) : "v"(p) : "memory");
  return v;
}

// 16 coherent dwordx4 loads, contiguous 256B, acked. "=&v": no alias w/ addr.
#define PLOADS16(T, ADDR)                                              \
  asm volatile(                                                        \
    "global_load_dwordx4 %0,  %16, off sc0 sc1\n\t"                    \
    "global_load_dwordx4 %1,  %16, off offset:16 sc0 sc1\n\t"          \
    "global_load_dwordx4 %2,  %16, off offset:32 sc0 sc1\n\t"          \
    "global_load_dwordx4 %3,  %16, off offset:48 sc0 sc1\n\t"          \
    "global_load_dwordx4 %4,  %16, off offset:64 sc0 sc1\n\t"          \
    "global_load_dwordx4 %5,  %16, off offset:80 sc0 sc1\n\t"          \
    "global_load_dwordx4 %6,  %16, off offset:96 sc0 sc1\n\t"          \
    "global_load_dwordx4 %7,  %16, off offset:112 sc0 sc1\n\t"         \
    "global_load_dwordx4 %8,  %16, off offset:128 sc0 sc1\n\t"         \
    "global_load_dwordx4 %9,  %16, off offset:144 sc0 sc1\n\t"         \
    "global_load_dwordx4 %10, %16, off offset:160 sc0 sc1\n\t"         \
    "global_load_dwordx4 %11, %16, off offset:176 sc0 sc1\n\t"         \
    "global_load_dwordx4 %12, %16, off offset:192 sc0 sc1\n\t"         \
    "global_load_dwordx4 %13, %16, off offset:208 sc0 sc1\n\t"         \
    "global_load_dwordx4 %14, %16, off offset:224 sc0 sc1\n\t"         \
    "global_load_dwordx4 %15, %16, off offset:240 sc0 sc1\n\t"         \
    "s_waitcnt vmcnt(0)"                                               \
    : "=&v"(T[0]),  "=&v"(T[1]),  "=&v"(T[2]),  "=&v"(T[3]),           \
      "=&v"(T[4]),  "=&v"(T[5]),  "=&v"(T[6]),  "=&v"(T[7]),           \
      "=&v"(T[8]),  "=&v"(T[9]),  "=&v"(T[10]), "=&v"(T[11]),          \
      "=&v"(T[12]), "=&v"(T[13]), "=&v"(T[14]), "=&v"(T[15])           \
    : "v"(ADDR) : "memory")

// 4 coherent 16B loads, contiguous 64B, acked
#define CLOADS4(T, ADDR)                                               \
  asm volatile(                                                        \
    "global_load_dwordx4 %0, %4, off sc0 sc1\n\t"                      \
    "global_load_dwordx4 %1, %4, off offset:16 sc0 sc1\n\t"            \
    "global_load_dwordx4 %2, %4, off offset:32 sc0 sc1\n\t"            \
    "global_load_dwordx4 %3, %4, off offset:48 sc0 sc1\n\t"            \
    "s_waitcnt vmcnt(0)"                                               \
    : "=&v"(T[0]), "=&v"(T[1]), "=&v"(T[2]), "=&v"(T[3])               \
    : "v"(ADDR) : "memory")

// tagged 8B store: {4B data, 4B tag} lands as one instruction, fire-and-forget
#define TSTORE(ADDR, VAL)                                              \
  asm volatile("global_store_dwordx2 %0, %1, off sc0 sc1"              \
               :: "v"(ADDR), "v"(VAL) : "memory")

#define DSTORE(ADDR, VAL)                                              \
  asm volatile("global_store_dword %0, %1, off sc0 sc1"                \
               :: "v"(ADDR), "v"(VAL) : "memory")

// ---------------------------------------------------------------------------
// Kernel 1: Xg[t][b][j] = x_t[b] @ W_ih^T [j] + b_ih[j] + b_hh[j]
// ---------------------------------------------------------------------------
__global__ __launch_bounds__(256) void k_xg(
    const float* __restrict__ img,   // [32][512]
    const int*   __restrict__ gt,    // [32][48]
    const float* __restrict__ emb,   // [32000][512]
    const float* __restrict__ W_ih,  // [2048][512]
    const float* __restrict__ b_ih,
    const float* __restrict__ b_hh,
    float* __restrict__ Xg)          // [48][32][2048]
{
  const int s    = blockIdx.x;
  const int lane = threadIdx.x & 63;
  const int wv   = threadIdx.x >> 6;
  const int nbase = blockIdx.y * 256 + wv * 64;
  const int lr  = lane & 15;
  const int lkb = lane >> 4;

  const float* arow[2];
#pragma unroll
  for (int m = 0; m < 2; ++m) {
    int b = m * 16 + lr;
    const float* src;
    if (s == 0) {
      src = img + b * E_;
    } else {
      int tok = (s == 1) ? 1 : gt[b * T_ + (s - 1)];
      src = emb + (long)tok * E_;
    }
    arow[m] = src;
  }

  f32x4 acc[2][4];
#pragma unroll
  for (int m = 0; m < 2; ++m)
#pragma unroll
    for (int n = 0; n < 4; ++n) acc[m][n] = (f32x4){0.f, 0.f, 0.f, 0.f};

  for (int kt = 0; kt < 16; ++kt) {
    int ko = kt * 32 + lkb * 8;
    bf16x8 a0 = load_cvt8(arow[0] + ko);
    bf16x8 a1 = load_cvt8(arow[1] + ko);
#pragma unroll
    for (int n = 0; n < 4; ++n) {
      const float* wp = W_ih + (long)(nbase + n * 16 + lr) * E_ + ko;
      bf16x8 bw = load_cvt8(wp);
      acc[0][n] = __builtin_amdgcn_mfma_f32_16x16x32_bf16(a0, bw, acc[0][n], 0, 0, 0);
      acc[1][n] = __builtin_amdgcn_mfma_f32_16x16x32_bf16(a1, bw, acc[1][n], 0, 0, 0);
    }
  }

#pragma unroll
  for (int n = 0; n < 4; ++n) {
    int j = nbase + n * 16 + lr;
    float bias = b_ih[j] + b_hh[j];
#pragma unroll
    for (int m = 0; m < 2; ++m) {
#pragma unroll
      for (int r = 0; r < 4; ++r) {
        int b = m * 16 + lkb * 4 + r;
        Xg[((long)(s * B_ + b) * 2048) + j] = acc[m][n][r] + bias;
      }
    }
  }
}

// ---------------------------------------------------------------------------
// Kernel 2 (fused):
//  blocks 0..63   : LSTM recurrence. WG w owns hidden dims [8w, 8w+8).
//                   h exchange via REP=8 replicated tagged units in hrepl
//                   (parity double-buffered); WG w polls replica w&7 only
//                   -> 8 readers per line. Stores fire-and-forget.
//  block 64       : aggregator. Polls 64 per-WG flag lines (1 reader each),
//                   publishes the min epoch to 64 replica lines.
//  blocks 65..314 : head GEMM consumers. tid0 polls ONE epoch replica line
//                   (~4 readers/line), then bulk-loads its hs tile sc0/sc1.
// Co-residency structural: 315 WGs x 68KB LDS -> 2 WG/CU -> capacity 512.
// ---------------------------------------------------------------------------
__global__ __launch_bounds__(256, 2) void k_fused(
    const float* __restrict__ W_hh,      // [2048][512]
    const float* __restrict__ Xg,        // [48][32][2048]
    const float* __restrict__ W_head,    // [32000][512]
    const float* __restrict__ b_head,    // [32000]
    unsigned* __restrict__ flags,        // [64] lines (128B apart)
    unsigned* __restrict__ replicas,     // [64] lines (128B apart)
    char* __restrict__ hrepl,            // [REP][2][32][256u] x 8B tagged
    unsigned short* __restrict__ hs,     // [1504][512] bf16 plain
    float* __restrict__ out)             // [48][32][32000]
{
  __shared__ __align__(16) char lds[69632];  // 32K wlds + 32K stage + 4K gbuf
  const int tid  = threadIdx.x;
  const int lane = tid & 63;
  const int wv   = tid >> 6;
  const int lr   = lane & 15;
  const int lkb  = lane >> 4;

  if (blockIdx.x < NWG) {
    // ===================== recurrence role =====================
    char* wlds  = lds;            // [2 pair][16 kt][64 lane][16B] = 32KB
    char* stage = lds + 32768;    // pure h [32 b][512 dim] bf16, swizzled
    char* gbufc = lds + 65536;    // [4 gate][32 b][8 dim] f32 = 4KB
    const int w = blockIdx.x;     // owns hidden dims [8w, 8w+8)
    const int p  = wv & 1;        // gate pair: gates 2p, 2p+1
    const int nt = wv >> 1;       // b-tile

    // preload W_hh fragments (waves 0,1 load pair wv)
    if (wv < 2) {
#pragma unroll
      for (int kt = 0; kt < 16; ++kt) {
        int g = 2 * wv + (lr >> 3);
        int row = g * 512 + w * 8 + (lr & 7);
        bf16x8 wf = load_cvt8(W_hh + (long)row * E_ + kt * 32 + lkb * 8);
        *(bf16x8*)(wlds + (((wv * 16 + kt) * 64) + lane) * 16) = wf;
      }
    }
    __syncthreads();

    // cell state: threads 0..127, b = tid>>2, local dims d0, d0+1
    const int cb_b  = tid >> 2;
    const int cb_d0 = (tid & 3) * 2;
    float c0 = 0.f, c1 = 0.f;

    for (int t = 0; t < T_; ++t) {
      const int bb = nt * 16 + lr;

      // Xg slice (cached loads; overlaps the poll)
      float4 xg = *(const float4*)(Xg + ((long)t * B_ + bb) * 2048 +
                                   (2 * p + (lkb >> 1)) * 512 + w * 8 + (lkb & 1) * 4);

      f32x4 acc = (f32x4){0.f, 0.f, 0.f, 0.f};

      if (t > 0) {
        // ---- poll replica (w&7), parity (t-1)&1, expect tag == t ----
        int b_own = tid >> 3;
        const char* pb = hrepl + (long)(w & 7) * 131072 + ((t - 1) & 1) * 65536 +
                         b_own * 2048 + (tid & 7) * 256;
        i32x4 u[16];
        while (true) {
          PLOADS16(u, pb);
          bool ok = true;
#pragma unroll
          for (int i = 0; i < 16; ++i)
            ok = ok && (u[i][1] == t) && (u[i][3] == t);
          if (ok) break;
          __builtin_amdgcn_s_sleep(1);
        }
        // ---- strip tags -> stage (pure bf16 [b][512], xor-swizzled) ----
        int j0b = (tid & 7) * 128;
#pragma unroll
        for (int c = 0; c < 8; ++c) {
          i32x4 pc = (i32x4){u[2 * c][0], u[2 * c][2], u[2 * c + 1][0], u[2 * c + 1][2]};
          *(i32x4*)(stage + b_own * 1024 + ((j0b + c * 16) ^ ((b_own & 7) << 4))) = pc;
        }
        __syncthreads();   // stage ready; also fences gbuf(t-1) cell reads

        // ---- MFMA: A = W rows (2 gates x 8 dims), B = h ----
#pragma unroll
        for (int kt = 0; kt < 16; ++kt) {
          bf16x8 a = *(const bf16x8*)(wlds + (((p * 16 + kt) * 64) + lane) * 16);
          i32x4 bv = *(const i32x4*)(stage + bb * 1024 +
                                     ((kt * 64 + lkb * 16) ^ ((bb & 7) << 4)));
          acc = __builtin_amdgcn_mfma_f32_16x16x32_bf16(a, *(bf16x8*)&bv, acc, 0, 0, 0);
        }
      }

      // add Xg, write gate exchange
      acc[0] += xg.x; acc[1] += xg.y; acc[2] += xg.z; acc[3] += xg.w;
      int gp = 2 * p + (lkb >> 1);
      *(f32x4*)(gbufc + (gp * 32 + bb) * 32 + (((lkb & 1) * 16) ^ ((bb & 1) << 4))) = acc;
      __syncthreads();

      // ---- cell update + stores (threads 0..127) ----
      if (tid < 128) {
        int b = cb_b, d0 = cb_d0;
        int blk = ((d0 >= 4) ? 16 : 0) ^ ((b & 1) << 4);
        int inn = (d0 & 3) * 4;
        float2 gi  = *(const float2*)(gbufc + (0 * 32 + b) * 32 + blk + inn);
        float2 gf  = *(const float2*)(gbufc + (1 * 32 + b) * 32 + blk + inn);
        float2 gg_ = *(const float2*)(gbufc + (2 * 32 + b) * 32 + blk + inn);
        float2 go  = *(const float2*)(gbufc + (3 * 32 + b) * 32 + blk + inn);

        float cn0 = sigf(gf.x) * c0 + sigf(gi.x) * tanh_fast(gg_.x);
        float cn1 = sigf(gf.y) * c1 + sigf(gi.y) * tanh_fast(gg_.y);
        c0 = cn0; c1 = cn1;
        unsigned short h0 = (unsigned short)f2bf(sigf(go.x) * tanh_fast(cn0));
        unsigned short h1 = (unsigned short)f2bf(sigf(go.y) * tanh_fast(cn1));
        unsigned pk = (unsigned)h0 | ((unsigned)h1 << 16);

        if (t < T_ - 1) {
          // replicated tagged h stores (parity t&1, tag t+1), fire-and-forget
          i32x2 unit;
          unit[0] = (int)pk;
          unit[1] = t + 1;
          long off = (t & 1) * 65536 + b * 2048 + (w * 4 + (tid & 3)) * 8;
#pragma unroll
          for (int r = 0; r < REP; ++r)
            TSTORE(hrepl + (long)r * 131072 + off, unit);
        }
        if (t >= 1) {
          // plain hs store for consumers
          unsigned short* hp = hs + ((long)(t - 1) * B_ + b) * H_ + w * 8 + d0;
          DSTORE(hp, pk);
        }
      }
      // ack all stores, then publish per-WG flag (consumer visibility chain)
      asm volatile("s_waitcnt vmcnt(0)" ::: "memory");
      __syncthreads();
      if (tid == 0) {
        unsigned val = (unsigned)(t + 1);
        DSTORE(flags + w * 32, val);
      }
    }
  } else if (blockIdx.x == NWG) {
    // ===================== aggregator role =====================
    if (tid < 64) {
      for (unsigned e = 2; e <= (unsigned)T_; ++e) {
        while (true) {
          unsigned f = prog_load(flags + lane * 32);   // lane <-> producer WG
          if (__ballot(f >= e) == ~0ULL) break;
          __builtin_amdgcn_s_sleep(2);
        }
        DSTORE(replicas + lane * 32, e);
      }
    }
  } else {
    // ===================== head-consumer role =====================
    char* stage = lds;                        // 16KB hs m-tile, swizzled
    const int cid = blockIdx.x - NWG - 1;     // 0..249, owns v [cid*128, +128)
    const int vA = cid * 128 + wv * 16 + lr;
    const int vB = vA + 64;

    bf16x8 bwA[16], bwB[16];
#pragma unroll
    for (int kt = 0; kt < 16; ++kt) {
      bwA[kt] = load_cvt8(W_head + (long)vA * E_ + kt * 32 + lkb * 8);
      bwB[kt] = load_cvt8(W_head + (long)vB * E_ + kt * 32 + lkb * 8);
    }
    float biasA = b_head[vA];
    float biasB = b_head[vB];

    for (int mt = 0; mt < 94; ++mt) {
      int tagneed = (mt * 16) / 32 + 2;   // epoch that publishes this tile
      if (tid == 0) {
        const unsigned* rp = replicas + (cid & 63) * 32;
        while (prog_load(rp) < (unsigned)tagneed)
          __builtin_amdgcn_s_sleep(32);
      }
      __syncthreads();   // release block; also guards stage reuse

      // bulk-load 16 hs rows (16KB) via coherent loads, xor-swizzled LDS
      const char* src = (const char*)(hs + (long)mt * 16 * H_) + tid * 64;
      i32x4 st[4];
      CLOADS4(st, src);
#pragma unroll
      for (int i = 0; i < 4; ++i) {
        int c = tid * 4 + i;
        int row = c >> 6;
        int cb  = (c & 63) * 16;
        *(i32x4*)(stage + row * 1024 + (cb ^ ((row & 7) << 4))) = st[i];
      }
      __syncthreads();

      f32x4 accA = (f32x4){biasA, biasA, biasA, biasA};
      f32x4 accB = (f32x4){biasB, biasB, biasB, biasB};
#pragma unroll
      for (int kt = 0; kt < 16; ++kt) {
        int cb = kt * 64 + lkb * 16;
        i32x4 av = *(const i32x4*)(stage + lr * 1024 + (cb ^ ((lr & 7) << 4)));
        bf16x8 a = *(bf16x8*)&av;
        accA = __builtin_amdgcn_mfma_f32_16x16x32_bf16(a, bwA[kt], accA, 0, 0, 0);
        accB = __builtin_amdgcn_mfma_f32_16x16x32_bf16(a, bwB[kt], accB, 0, 0, 0);
      }

#pragma unroll
      for (int r = 0; r < 4; ++r) {
        int R = mt * 16 + lkb * 4 + r;          // hs row; out row = R + 32
        out[(long)(R + 32) * V_ + vA] = accA[r];
        out[(long)(R + 32) * V_ + vB] = accB[r];
      }
    }
  }
}

// ---------------------------------------------------------------------------
extern "C" void kernel_launch(void* const* d_in, const int* in_sizes, int n_in,
                              void* d_out, int out_size, void* d_ws, size_t ws_size,
                              hipStream_t stream) {
  const float* img  = (const float*)d_in[0];
  const int*   gt   = (const int*)d_in[1];
  const float* emb  = (const float*)d_in[2];
  const float* W_ih = (const float*)d_in[3];
  const float* W_hh = (const float*)d_in[4];
  const float* b_ih = (const float*)d_in[5];
  const float* b_hh = (const float*)d_in[6];
  const float* W_hd = (const float*)d_in[7];
  const float* b_hd = (const float*)d_in[8];
  float* out = (float*)d_out;

  char* ws = (char*)d_ws;
  unsigned*       flags = (unsigned*)(ws);                   // 8192 B (64 x 128B)
  unsigned*       repl  = (unsigned*)(ws + 8192);            // 8192 B (64 x 128B)
  char*           hrepl = ws + 16384;                        // 8*131072 = 1048576 B
  unsigned short* hs    = (unsigned short*)(ws + 16384 + 1048576);   // 1540096 B
  float*          Xg    = (float*)(ws + 16384 + 1048576 + 1540096);  // 12582912 B

  hipMemsetAsync(ws, 0, 16384, stream);                      // flags + replicas
  hipMemsetAsync(out, 0, (size_t)B_ * V_ * sizeof(float), stream);  // outputs[0]=0

  dim3 g1(48, 8);
  k_xg<<<g1, 256, 0, stream>>>(img, gt, emb, W_ih, b_ih, b_hh, Xg);
  k_fused<<<GRID, 256, 0, stream>>>(W_hh, Xg, W_hd, b_hd, flags, repl, hrepl, hs, out);
}